// Round 1
// baseline (3341.014 us; speedup 1.0000x reference)
//
#include <hip/hip_runtime.h>

// GCN GraphConv (norm='both', mult-first): out = relu( D_in^-1/2 * A * D_out^-1/2 * (X W) + b )
// N=100000 nodes, E=3200000 edges, IN=128, OUT=64, fp32.

constexpr int N_NODES = 100000;
constexpr int N_EDGES = 3200000;
constexpr int IN_F    = 128;
constexpr int OUT_F   = 64;

// ---- Kernel 1: degree histogram (float atomics; exact for counts < 2^24) ----
__global__ void deg_kernel(const int* __restrict__ src, const int* __restrict__ dst,
                           float* __restrict__ deg_out, float* __restrict__ deg_in) {
    int e = blockIdx.x * blockDim.x + threadIdx.x;
    if (e < N_EDGES) {
        atomicAdd(&deg_out[src[e]], 1.0f);
        atomicAdd(&deg_in[dst[e]], 1.0f);
    }
}

// ---- Kernel 2: sxw[n, :] = (X[n, :] @ W) * rsqrt(max(deg_out[n], 1)) ----
// One thread per output element. W (128x64 fp32 = 32 KB) staged in LDS.
// All 64 lanes of a wave share one row -> X reads are wave-broadcast (L1 hit).
__global__ void gemm_scale_kernel(const float* __restrict__ x, const float* __restrict__ W,
                                  const float* __restrict__ deg_out, float* __restrict__ sxw) {
    __shared__ float Wl[IN_F * OUT_F];
    for (int i = threadIdx.x; i < IN_F * OUT_F; i += blockDim.x) Wl[i] = W[i];
    __syncthreads();

    int id  = blockIdx.x * blockDim.x + threadIdx.x;
    int row = id >> 6;   // /64
    int col = id & 63;
    if (row >= N_NODES) return;

    const float* xr = x + (long)row * IN_F;
    float acc = 0.0f;
#pragma unroll
    for (int k = 0; k < IN_F; ++k) acc += xr[k] * Wl[k * OUT_F + col];

    float d = deg_out[row];
    float s = rsqrtf(d < 1.0f ? 1.0f : d);
    sxw[(long)row * OUT_F + col] = acc * s;
}

// ---- Kernel 3: out[dst[e], :] += sxw[src[e], :]  via fp32 atomics ----
// 16 threads per edge, each handles a float4 chunk (4 atomics).
__global__ void scatter_kernel(const int* __restrict__ src, const int* __restrict__ dst,
                               const float* __restrict__ sxw, float* __restrict__ out) {
    long id = (long)blockIdx.x * blockDim.x + threadIdx.x;
    long e  = id >> 4;
    int  g  = (int)(id & 15);
    if (e >= N_EDGES) return;

    int s = src[e];
    int d = dst[e];
    float4 v = ((const float4*)(sxw + (long)s * OUT_F))[g];
    float* o = out + (long)d * OUT_F + g * 4;
    atomicAdd(o + 0, v.x);
    atomicAdd(o + 1, v.y);
    atomicAdd(o + 2, v.z);
    atomicAdd(o + 3, v.w);
}

// ---- Kernel 4: out = relu(out * rsqrt(max(deg_in,1)) + b) ----
__global__ void final_kernel(const float* __restrict__ deg_in, const float* __restrict__ b,
                             float* __restrict__ out) {
    int id = blockIdx.x * blockDim.x + threadIdx.x;
    if (id >= N_NODES * OUT_F) return;
    int row = id >> 6;
    int col = id & 63;
    float d = deg_in[row];
    float s = rsqrtf(d < 1.0f ? 1.0f : d);
    float v = out[id] * s + b[col];
    out[id] = v > 0.0f ? v : 0.0f;
}

extern "C" void kernel_launch(void* const* d_in, const int* in_sizes, int n_in,
                              void* d_out, int out_size, void* d_ws, size_t ws_size,
                              hipStream_t stream) {
    const float* in_feat = (const float*)d_in[0];
    const int*   src     = (const int*)d_in[1];
    const int*   dst     = (const int*)d_in[2];
    const float* W       = (const float*)d_in[3];
    const float* b       = (const float*)d_in[4];
    float*       out     = (float*)d_out;

    // ws layout: sxw [N*64 fp32] | deg_out [N fp32] | deg_in [N fp32]
    float* sxw     = (float*)d_ws;
    float* deg_out = sxw + (size_t)N_NODES * OUT_F;
    float* deg_in  = deg_out + N_NODES;

    // ws/out are poisoned 0xAA before every timed launch -> zero what we accumulate into.
    hipMemsetAsync(deg_out, 0, 2 * (size_t)N_NODES * sizeof(float), stream);
    hipMemsetAsync(d_out, 0, (size_t)N_NODES * OUT_F * sizeof(float), stream);

    deg_kernel<<<(N_EDGES + 255) / 256, 256, 0, stream>>>(src, dst, deg_out, deg_in);

    gemm_scale_kernel<<<(N_NODES * OUT_F + 255) / 256, 256, 0, stream>>>(
        in_feat, W, deg_out, sxw);

    long scatter_threads = (long)N_EDGES * 16;
    scatter_kernel<<<(unsigned)((scatter_threads + 255) / 256), 256, 0, stream>>>(
        src, dst, sxw, out);

    final_kernel<<<(N_NODES * OUT_F + 255) / 256, 256, 0, stream>>>(deg_in, b, out);
}

// Round 2
// 882.582 us; speedup vs baseline: 3.7855x; 3.7855x over previous
//
#include <hip/hip_runtime.h>

// GCN GraphConv (norm='both', mult-first): out = relu( D_in^-1/2 * A * D_out^-1/2 * (X W) + b )
// N=100000 nodes, E=3200000 edges, IN=128, OUT=64, fp32.
//
// Strategy R2: no fp32 atomic scatter. Build CSR-by-dst (deg -> scan -> fill),
// then gather-sum per dst node (fused with in-degree norm, bias, relu).

constexpr int N_NODES = 100000;
constexpr int N_EDGES = 3200000;
constexpr int IN_F    = 128;
constexpr int OUT_F   = 64;

// ---- Kernel 1: degree histogram (int atomics) ----
__global__ void deg_kernel(const int* __restrict__ src, const int* __restrict__ dst,
                           int* __restrict__ deg_out_i, int* __restrict__ deg_in_i) {
    int e = blockIdx.x * blockDim.x + threadIdx.x;
    if (e < N_EDGES) {
        atomicAdd(&deg_out_i[src[e]], 1);
        atomicAdd(&deg_in_i[dst[e]], 1);
    }
}

// ---- Kernel 2: single-block exclusive scan of deg_in_i -> row_ptr[0..N] ----
// Wave-shuffle inclusive scan per 1024-chunk; running carry across chunks.
__global__ void scan_kernel(const int* __restrict__ deg_in_i, int* __restrict__ row_ptr) {
    __shared__ int wsum[16];
    __shared__ int carry;
    const int tid  = threadIdx.x;           // 0..1023
    const int lane = tid & 63;
    const int wid  = tid >> 6;              // 0..15

    if (tid == 0) { carry = 0; row_ptr[0] = 0; }
    __syncthreads();

    for (int base = 0; base < N_NODES; base += 1024) {
        int i = base + tid;
        int v = (i < N_NODES) ? deg_in_i[i] : 0;
        // inclusive scan within wave (64 lanes)
        #pragma unroll
        for (int off = 1; off < 64; off <<= 1) {
            int t = __shfl_up(v, off);
            if (lane >= off) v += t;
        }
        if (lane == 63) wsum[wid] = v;
        __syncthreads();
        if (wid == 0 && lane < 16) {
            int s = wsum[lane];
            #pragma unroll
            for (int off = 1; off < 16; off <<= 1) {
                int t = __shfl_up(s, off);
                if (lane >= off) s += t;
            }
            wsum[lane] = s;
        }
        __syncthreads();
        int inc = v + (wid ? wsum[wid - 1] : 0);
        if (i < N_NODES) row_ptr[i + 1] = carry + inc;
        __syncthreads();
        if (tid == 0) carry += wsum[15];    // chunk total
        __syncthreads();
    }
}

// ---- Kernel 3: fill CSR edge array sorted by dst ----
// cur[] starts as a copy of row_ptr[0..N-1].
__global__ void fill_kernel(const int* __restrict__ src, const int* __restrict__ dst,
                            int* __restrict__ cur, int* __restrict__ csr_src) {
    int e = blockIdx.x * blockDim.x + threadIdx.x;
    if (e < N_EDGES) {
        int p = atomicAdd(&cur[dst[e]], 1);
        csr_src[p] = src[e];
    }
}

// ---- Kernel 4: sxw[n,:] = (X[n,:] @ W) * rsqrt(max(deg_out[n],1)) ----
// Persistent blocks; W staged once per block in LDS; X rows staged coalesced.
__global__ __launch_bounds__(256) void gemm_scale_kernel(
        const float* __restrict__ x, const float* __restrict__ W,
        const int* __restrict__ deg_out_i, float* __restrict__ sxw) {
    __shared__ float Wl[IN_F * OUT_F];   // 32 KB
    __shared__ float xl[4 * IN_F];       // 2 KB, 4 rows per group
    const int tid = threadIdx.x;
    for (int i = tid; i < IN_F * OUT_F; i += 256) Wl[i] = W[i];

    const int row = tid >> 6;            // 0..3 (wave-uniform)
    const int col = tid & 63;
    const int n_groups = N_NODES / 4;    // 25000, exact

    for (int rg = blockIdx.x; rg < n_groups; rg += gridDim.x) {
        __syncthreads();                 // protect xl from previous iteration
        const long base = (long)rg * 4 * IN_F;
        xl[tid]       = x[base + tid];
        xl[tid + 256] = x[base + tid + 256];
        __syncthreads();

        float acc = 0.0f;
        const float4* xv = (const float4*)&xl[row * IN_F];
        #pragma unroll
        for (int k4 = 0; k4 < IN_F / 4; ++k4) {
            float4 xk = xv[k4];
            acc += xk.x * Wl[(k4 * 4 + 0) * OUT_F + col];
            acc += xk.y * Wl[(k4 * 4 + 1) * OUT_F + col];
            acc += xk.z * Wl[(k4 * 4 + 2) * OUT_F + col];
            acc += xk.w * Wl[(k4 * 4 + 3) * OUT_F + col];
        }
        const int g_row = rg * 4 + row;
        float d = (float)deg_out_i[g_row];
        float s = rsqrtf(d < 1.0f ? 1.0f : d);
        sxw[(long)g_row * OUT_F + col] = acc * s;
    }
}

// ---- Kernel 5: gather-sum per dst node, fused norm+bias+relu ----
// One wave per node; lane = output column. deg_in comes from row_ptr diff.
__global__ __launch_bounds__(256) void gather_kernel(
        const int* __restrict__ row_ptr, const int* __restrict__ csr_src,
        const float* __restrict__ sxw, const float* __restrict__ b,
        float* __restrict__ out) {
    const int lane = threadIdx.x & 63;
    const int node = blockIdx.x * 4 + (threadIdx.x >> 6);
    if (node >= N_NODES) return;

    const int beg = row_ptr[node];
    const int end = row_ptr[node + 1];
    float acc = 0.0f;
    int j = beg;
    for (; j + 4 <= end; j += 4) {
        int s0 = csr_src[j + 0];
        int s1 = csr_src[j + 1];
        int s2 = csr_src[j + 2];
        int s3 = csr_src[j + 3];
        float v0 = sxw[(long)s0 * OUT_F + lane];
        float v1 = sxw[(long)s1 * OUT_F + lane];
        float v2 = sxw[(long)s2 * OUT_F + lane];
        float v3 = sxw[(long)s3 * OUT_F + lane];
        acc += v0; acc += v1; acc += v2; acc += v3;
    }
    for (; j < end; ++j) acc += sxw[(long)csr_src[j] * OUT_F + lane];

    float d = (float)(end - beg);
    float s = rsqrtf(d < 1.0f ? 1.0f : d);
    float v = acc * s + b[lane];
    out[(long)node * OUT_F + lane] = v > 0.0f ? v : 0.0f;
}

extern "C" void kernel_launch(void* const* d_in, const int* in_sizes, int n_in,
                              void* d_out, int out_size, void* d_ws, size_t ws_size,
                              hipStream_t stream) {
    const float* in_feat = (const float*)d_in[0];
    const int*   src     = (const int*)d_in[1];
    const int*   dst     = (const int*)d_in[2];
    const float* W       = (const float*)d_in[3];
    const float* b       = (const float*)d_in[4];
    float*       out     = (float*)d_out;

    // ws layout: sxw [N*64 f32] | deg_out_i [N] | deg_in_i/cur [N] | row_ptr [N+1] | csr_src [E]
    float* sxw       = (float*)d_ws;
    int*   deg_out_i = (int*)(sxw + (size_t)N_NODES * OUT_F);
    int*   deg_in_i  = deg_out_i + N_NODES;          // reused as `cur` after scan
    int*   row_ptr   = deg_in_i + N_NODES;
    int*   csr_src   = row_ptr + (N_NODES + 1);

    // zero the two degree arrays (ws is poisoned 0xAA before every timed launch)
    hipMemsetAsync(deg_out_i, 0, 2 * (size_t)N_NODES * sizeof(int), stream);

    deg_kernel<<<(N_EDGES + 255) / 256, 256, 0, stream>>>(src, dst, deg_out_i, deg_in_i);

    scan_kernel<<<1, 1024, 0, stream>>>(deg_in_i, row_ptr);

    // cur = row_ptr[0..N-1] (overwrites deg_in_i, which is now dead)
    hipMemcpyAsync(deg_in_i, row_ptr, (size_t)N_NODES * sizeof(int),
                   hipMemcpyDeviceToDevice, stream);

    gemm_scale_kernel<<<2048, 256, 0, stream>>>(in_feat, W, deg_out_i, sxw);

    fill_kernel<<<(N_EDGES + 255) / 256, 256, 0, stream>>>(src, dst, deg_in_i, csr_src);

    gather_kernel<<<(N_NODES + 3) / 4, 256, 0, stream>>>(row_ptr, csr_src, sxw, b, out);
}